// Round 7
// baseline (605.856 us; speedup 1.0000x reference)
//
#include <hip/hip_runtime.h>
#include <hip/hip_bf16.h>

#define INFV 1e9f
#define EPSV 1e-5f

typedef unsigned short u16;
typedef unsigned int u32;
typedef __attribute__((ext_vector_type(8))) short short8;   // 8 bf16 (MFMA A/B frag)
typedef __attribute__((ext_vector_type(4))) float float4v;  // MFMA C/D frag

__device__ __forceinline__ u16 f2us(float f) {
    u32 v;
    __builtin_memcpy(&v, &f, 4);
    u32 r = v + 0x7fffu + ((v >> 16) & 1u);
    return (u16)(r >> 16);
}

__device__ __forceinline__ float wred_sum(float x) {
    #pragma unroll
    for (int o = 32; o; o >>= 1) x += __shfl_xor(x, o);
    return x;
}
__device__ __forceinline__ float wred_max(float x) {
    #pragma unroll
    for (int o = 32; o; o >>= 1) x = fmaxf(x, __shfl_xor(x, o));
    return x;
}

// ---------------- LN(m) -> mn bf16, + weight prep (verbatim round 5) ----------------
__global__ __launch_bounds__(256) void k_prep_ln(
    const float* __restrict__ m, const float* __restrict__ gm, const float* __restrict__ bm,
    u16* __restrict__ mn,
    const float* __restrict__ wv, const float* __restrict__ wg,
    const float* __restrict__ wo, const float* __restrict__ wz,
    u16* __restrict__ wv_t, u16* __restrict__ wg_t,
    u16* __restrict__ wo_t, u16* __restrict__ wzT)
{
    if (blockIdx.x < 12288) {
        const int tid  = threadIdx.x;
        const int wid  = tid >> 6;
        const int lane = tid & 63;
        const int rloc = lane >> 4;
        const int c4   = (lane & 15) * 4;
        const int row  = blockIdx.x * 16 + wid * 4 + rloc;
        const float4 x = *(const float4*)(m + (size_t)row * 64 + c4);
        float s1 = x.x + x.y + x.z + x.w;
        float s2 = x.x * x.x + x.y * x.y + x.z * x.z + x.w * x.w;
        #pragma unroll
        for (int o = 8; o; o >>= 1) { s1 += __shfl_xor(s1, o); s2 += __shfl_xor(s2, o); }
        const float mean = s1 * (1.0f / 64.0f);
        const float var  = s2 * (1.0f / 64.0f) - mean * mean;
        const float rs   = rsqrtf(var + EPSV);
        const float4 g = *(const float4*)(gm + c4);
        const float4 b = *(const float4*)(bm + c4);
        uint2 pk;
        pk.x = (u32)f2us((x.x - mean) * rs * g.x + b.x) | ((u32)f2us((x.y - mean) * rs * g.y + b.y) << 16);
        pk.y = (u32)f2us((x.z - mean) * rs * g.z + b.z) | ((u32)f2us((x.w - mean) * rs * g.w + b.w) << 16);
        *(uint2*)(mn + (size_t)row * 64 + c4) = pk;
    } else {
        const int i = (blockIdx.x - 12288) * 256 + threadIdx.x;
        if (i < 16384) {
            const int n = i >> 6, k = i & 63;
            wv_t[i] = f2us(wv[(size_t)k * 256 + n]);
        } else if (i < 32768) {
            const int j = i - 16384, n = j >> 6, k = j & 63;
            wg_t[j] = f2us(wg[(size_t)k * 256 + n]);
        } else if (i < 49152) {
            const int j = i - 32768, n = j >> 8, k = j & 255;
            wo_t[j] = f2us(wo[(size_t)k * 64 + n]);
        } else if (i < 51200) {
            const int j = i - 49152, n = j >> 7, k = j & 127;
            wzT[j] = (n < 8) ? f2us(wz[(size_t)k * 8 + n]) : (u16)0;
        }
    }
}

// ---------------- logits via MFMA (verbatim round 5); wbuf [h][pair] fp32 ----------------
__global__ __launch_bounds__(256) void k_logits2(
    const float* __restrict__ z, const float* __restrict__ mask,
    const float* __restrict__ gz, const float* __restrict__ bz,
    const u16* __restrict__ wzT, const float* __restrict__ bzb,
    float* __restrict__ wbuf)
{
    const int tid   = threadIdx.x;
    const int wid   = tid >> 6;
    const int lane  = tid & 63;
    const int lrow  = lane & 15;
    const int lkg   = lane >> 4;
    const int pair0 = (blockIdx.x * 4 + wid) * 16;

    float x[4][8];
    float s1 = 0.0f, s2 = 0.0f;
    #pragma unroll
    for (int ks = 0; ks < 4; ks++) {
        const float4* zp = (const float4*)(z + (size_t)(pair0 + lrow) * 128 + ks * 32 + lkg * 8);
        const float4 a = zp[0], b = zp[1];
        x[ks][0] = a.x; x[ks][1] = a.y; x[ks][2] = a.z; x[ks][3] = a.w;
        x[ks][4] = b.x; x[ks][5] = b.y; x[ks][6] = b.z; x[ks][7] = b.w;
        #pragma unroll
        for (int j = 0; j < 8; j++) { s1 += x[ks][j]; s2 += x[ks][j] * x[ks][j]; }
    }
    s1 += __shfl_xor(s1, 16); s1 += __shfl_xor(s1, 32);
    s2 += __shfl_xor(s2, 16); s2 += __shfl_xor(s2, 32);
    const float mean = s1 * (1.0f / 128.0f);
    const float var  = s2 * (1.0f / 128.0f) - mean * mean;
    const float rs   = rsqrtf(var + EPSV);

    float4v acc = (float4v){0.f, 0.f, 0.f, 0.f};
    #pragma unroll
    for (int ks = 0; ks < 4; ks++) {
        const int c0 = ks * 32 + lkg * 8;
        const float4 g0 = *(const float4*)(gz + c0);
        const float4 g1 = *(const float4*)(gz + c0 + 4);
        const float4 b0 = *(const float4*)(bz + c0);
        const float4 b1 = *(const float4*)(bz + c0 + 4);
        const float gv[8]  = {g0.x, g0.y, g0.z, g0.w, g1.x, g1.y, g1.z, g1.w};
        const float bvv[8] = {b0.x, b0.y, b0.z, b0.w, b1.x, b1.y, b1.z, b1.w};
        short8 afr;
        #pragma unroll
        for (int j = 0; j < 8; j++)
            afr[j] = (short)f2us((x[ks][j] - mean) * rs * gv[j] + bvv[j]);
        const short8 bfr = *(const short8*)(wzT + (size_t)lrow * 128 + c0);
        acc = __builtin_amdgcn_mfma_f32_16x16x32_bf16(afr, bfr, acc, 0, 0, 0);
    }
    if (lrow < 8) {
        const float bzv = bzb[lrow];
        #pragma unroll
        for (int r = 0; r < 4; r++) {
            const int p = pair0 + lkg * 4 + r;
            const float mb = INFV * (mask[p] - 1.0f);
            wbuf[(size_t)lrow * 147456 + p] = acc[r] + bzv + mb;
        }
    }
}

// ---------------- softmax (verbatim round 5); fp32 -> bf16 ----------------
__global__ __launch_bounds__(256) void k_softmax(
    const float* __restrict__ wbuf, u16* __restrict__ wb16)
{
    const int r = blockIdx.x * 4 + (threadIdx.x >> 6);
    const int lane = threadIdx.x & 63;
    const float* base = wbuf + (size_t)r * 384;
    float v[6];
    float mx = -1e30f;
    #pragma unroll
    for (int j = 0; j < 6; j++) {
        v[j] = base[lane + j * 64];
        mx = fmaxf(mx, v[j]);
    }
    mx = wred_max(mx);
    float s = 0.0f;
    #pragma unroll
    for (int j = 0; j < 6; j++) {
        v[j] = __expf(v[j] - mx);
        s += v[j];
    }
    s = wred_sum(s);
    const float inv = 1.0f / s;
    u16* ob = wb16 + (size_t)r * 384;
    #pragma unroll
    for (int j = 0; j < 6; j++) ob[lane + j * 64] = f2us(v[j] * inv);
}

// ---------------- k_vt: v-GEMM (extracted verbatim from round-5 k_fused4) ----------------
// block = one (s, 32-k chunk); A from mn (global), B from wv_t; store v_t[s][hc][k] bf16.
__global__ __launch_bounds__(256) void k_vt(
    const u16* __restrict__ mn, const u16* __restrict__ wv_t,
    u16* __restrict__ v_t)
{
    const int tid  = threadIdx.x;
    const int wid  = tid >> 6;
    const int lane = tid & 63;
    const int lrow = lane & 15;
    const int lkg  = lane >> 4;
    const int s    = blockIdx.x / 12;
    const int k0   = (blockIdx.x % 12) * 32;

    const int vmt  = wid & 1;
    const int vnt0 = (wid >> 1) * 8;

    float4v vacc[8];
    #pragma unroll
    for (int nt = 0; nt < 8; nt++) vacc[nt] = (float4v){0.f, 0.f, 0.f, 0.f};
    const u16* mnk = mn + ((size_t)s * 384 + k0 + vmt * 16 + lrow) * 64;
    #pragma unroll
    for (int ks = 0; ks < 2; ks++) {
        const short8 a = *(const short8*)(mnk + ks * 32 + lkg * 8);
        #pragma unroll
        for (int nt = 0; nt < 8; nt++) {
            const short8 b = *(const short8*)(wv_t + (size_t)((vnt0 + nt) * 16 + lrow) * 64 + ks * 32 + lkg * 8);
            vacc[nt] = __builtin_amdgcn_mfma_f32_16x16x32_bf16(a, b, vacc[nt], 0, 0, 0);
        }
    }
    // store: v value for k = k0 + vmt*16 + lkg*4 + r, hc = (vnt0+nt)*16 + lrow
    #pragma unroll
    for (int nt = 0; nt < 8; nt++) {
        uint2 pk;
        pk.x = (u32)f2us(vacc[nt][0]) | ((u32)f2us(vacc[nt][1]) << 16);
        pk.y = (u32)f2us(vacc[nt][2]) | ((u32)f2us(vacc[nt][3]) << 16);
        *(uint2*)(v_t + ((size_t)s * 256 + (vnt0 + nt) * 16 + lrow) * 384 + k0 + vmt * 16 + lkg * 4) = pk;
    }
}

// ---------------- k_fused6: round-5 k_fused4 with in-loop v-GEMM/LDS/barriers removed ----------------
// B-frags come from v_t (global) instead of LDS vtt — same values, same MFMA pairing.
__global__ __launch_bounds__(256, 2) void k_fused6(
    const u16* __restrict__ mn,
    const float* __restrict__ bv, const float* __restrict__ bg, const float* __restrict__ bo,
    const u16* __restrict__ wg_t, const u16* __restrict__ wo_t,
    const u16* __restrict__ v_t, const u16* __restrict__ wb16,
    float* __restrict__ out)
{
    __shared__ __align__(16) u16 og[128 * 264];   // epilogue o*g tile, 67584 B

    const int tid  = threadIdx.x;
    const int wid  = tid >> 6;
    const int lane = tid & 63;
    const int lrow = lane & 15;
    const int lkg  = lane >> 4;
    const int s    = blockIdx.y;
    const int q0   = blockIdx.x * 128;

    const u16* vts = v_t + (size_t)s * 98304;

    float4v oacc[32];
    #pragma unroll
    for (int mt = 0; mt < 2; mt++)
        #pragma unroll
        for (int nt = 0; nt < 16; nt++) {
            const float b = bv[nt * 16 + lrow];
            oacc[mt * 16 + nt] = (float4v){b, b, b, b};
        }

    for (int kt = 0; kt < 12; kt++) {
        const int k0 = kt * 32;
        short8 ah[2][8];
        #pragma unroll
        for (int mt = 0; mt < 2; mt++)
            #pragma unroll
            for (int h = 0; h < 8; h++)
                ah[mt][h] = *(const short8*)(wb16 + (size_t)h * 147456
                              + (size_t)(q0 + wid * 32 + mt * 16 + lrow) * 384 + k0 + lkg * 8);
        #pragma unroll
        for (int nt = 0; nt < 16; nt++) {
            const short8 b = *(const short8*)(vts + (size_t)(nt * 16 + lrow) * 384 + k0 + lkg * 8);
            oacc[nt]      = __builtin_amdgcn_mfma_f32_16x16x32_bf16(ah[0][nt >> 1], b, oacc[nt], 0, 0, 0);
            oacc[16 + nt] = __builtin_amdgcn_mfma_f32_16x16x32_bf16(ah[1][nt >> 1], b, oacc[16 + nt], 0, 0, 0);
        }
    }

    // ---- epilogue: verbatim round-5 k_fused4 ----
    #pragma unroll
    for (int mt = 0; mt < 2; mt++) {
        const u16* mnq = mn + ((size_t)s * 384 + q0 + wid * 32 + mt * 16 + lrow) * 64;
        const short8 a0 = *(const short8*)(mnq + lkg * 8);
        const short8 a1 = *(const short8*)(mnq + 32 + lkg * 8);
        #pragma unroll
        for (int nt = 0; nt < 16; nt++) {
            const float bgv = bg[nt * 16 + lrow];
            float4v gacc = (float4v){bgv, bgv, bgv, bgv};
            const short8 b0 = *(const short8*)(wg_t + (size_t)(nt * 16 + lrow) * 64 + lkg * 8);
            const short8 b1 = *(const short8*)(wg_t + (size_t)(nt * 16 + lrow) * 64 + 32 + lkg * 8);
            gacc = __builtin_amdgcn_mfma_f32_16x16x32_bf16(a0, b0, gacc, 0, 0, 0);
            gacc = __builtin_amdgcn_mfma_f32_16x16x32_bf16(a1, b1, gacc, 0, 0, 0);
            #pragma unroll
            for (int r = 0; r < 4; r++) {
                const float sg = 1.0f / (1.0f + __expf(-gacc[r]));
                og[(size_t)(wid * 32 + mt * 16 + lkg * 4 + r) * 264 + nt * 16 + lrow]
                    = f2us(oacc[mt * 16 + nt][r] * sg);
            }
        }
    }
    __syncthreads();

    #pragma unroll
    for (int mt = 0; mt < 2; mt++) {
        short8 af[8];
        #pragma unroll
        for (int ks = 0; ks < 8; ks++)
            af[ks] = *(const short8*)&og[(size_t)(wid * 32 + mt * 16 + lrow) * 264 + ks * 32 + lkg * 8];
        #pragma unroll
        for (int nt = 0; nt < 4; nt++) {
            const float bov = bo[nt * 16 + lrow];
            float4v fac = (float4v){bov, bov, bov, bov};
            #pragma unroll
            for (int ks = 0; ks < 8; ks++) {
                const short8 b = *(const short8*)(wo_t + (size_t)(nt * 16 + lrow) * 256 + ks * 32 + lkg * 8);
                fac = __builtin_amdgcn_mfma_f32_16x16x32_bf16(af[ks], b, fac, 0, 0, 0);
            }
            #pragma unroll
            for (int r = 0; r < 4; r++)
                out[((size_t)s * 384 + q0 + wid * 32 + mt * 16 + lkg * 4 + r) * 64 + nt * 16 + lrow]
                    = fac[r];
        }
    }
}

extern "C" void kernel_launch(void* const* d_in, const int* in_sizes, int n_in,
                              void* d_out, int out_size, void* d_ws, size_t ws_size,
                              hipStream_t stream) {
    const float* m    = (const float*)d_in[0];
    const float* z    = (const float*)d_in[1];
    const float* mask = (const float*)d_in[2];
    const float* gm   = (const float*)d_in[3];
    const float* bm   = (const float*)d_in[4];
    const float* gz   = (const float*)d_in[5];
    const float* bz   = (const float*)d_in[6];
    const float* wz   = (const float*)d_in[7];
    const float* bzb  = (const float*)d_in[8];
    const float* wv   = (const float*)d_in[9];
    const float* bv   = (const float*)d_in[10];
    const float* wg   = (const float*)d_in[11];
    const float* bg   = (const float*)d_in[12];
    const float* wo   = (const float*)d_in[13];
    const float* bo   = (const float*)d_in[14];
    float* out = (float*)d_out;
    char* ws = (char*)d_ws;

    // ws layout, total 128,290,816 B (proven available in round 6):
    //   wb16 @0                 [8][147456] bf16        2,359,296
    //   mn   @2359296           [196608][64] bf16      25,165,824
    //   v_t  @27525120          [512][256][384] bf16  100,663,296
    //     (wbuf fp32 logits ALIASES v_t's space: dead before k_vt writes)
    //   wv_t @128188416, wg_t @128221184, wo_t @128253952, wzT @128286720
    u16*  wb16 = (u16*)ws;
    u16*  mn   = (u16*)(ws + 2359296);
    u16*  v_t  = (u16*)(ws + 27525120);
    float* wbuf = (float*)(ws + 27525120);          // aliases v_t (sequential lifetimes)
    u16*  wv_t = (u16*)(ws + 128188416);
    u16*  wg_t = (u16*)(ws + 128221184);
    u16*  wo_t = (u16*)(ws + 128253952);
    u16*  wzT  = (u16*)(ws + 128286720);

    k_prep_ln<<<12488, 256, 0, stream>>>(m, gm, bm, mn, wv, wg, wo, wz, wv_t, wg_t, wo_t, wzT);
    k_logits2<<<2304,  256, 0, stream>>>(z, mask, gz, bz, wzT, bzb, wbuf);
    k_softmax<<<768,   256, 0, stream>>>(wbuf, wb16);
    k_vt     <<<6144,  256, 0, stream>>>(mn, wv_t, v_t);
    k_fused6 <<<dim3(3, 512), 256, 0, stream>>>(mn, bv, bg, bo, wg_t, wo_t, v_t, wb16, out);
}